// Round 7
// baseline (207.407 us; speedup 1.0000x reference)
//
#include <hip/hip_runtime.h>
#include <math.h>

#define HC     128    // HEADS*OUT_CH
#define SLOT   64     // bucket row stride = max(in-deg+1); Poisson(16): P(>63) ~ 5e-19
#define AGG_BLOCKS 2048
#define PREP_GRID  2048
#define NPART  8      // destination windows == XCD count

typedef unsigned int uint32;
typedef unsigned long long uint64;
typedef short bf16x8 __attribute__((ext_vector_type(8)));
typedef float f32x4 __attribute__((ext_vector_type(4)));

__device__ inline unsigned short f2bf(float f){
  uint32 u = __float_as_uint(f);
  u = (u + 0x7fffu + ((u >> 16) & 1u)) >> 16;
  return (unsigned short)u;
}
__device__ inline uint32 pack_bf2(float a, float b){
  return (uint32)f2bf(a) | ((uint32)f2bf(b) << 16);
}
// intra-wave LDS ordering (wave-private slices; no cross-wave barrier needed)
__device__ inline void lds_fence(){
  asm volatile("s_waitcnt lgkmcnt(0)" ::: "memory");
  __builtin_amdgcn_sched_barrier(0);
}

// ---------------- fused prep: MFMA GEMM tile + XCD-partitioned bucket fill ----------------
// blocks < ntiles: one 64-node GEMM tile, then fill chunk. blocks >= ntiles: fill only.
// fill: block b handles edge chunk b/8, dest window b%8 (window -> one XCD's L2).

__global__ __launch_bounds__(256) void k_prep(const float* __restrict__ x, const float* __restrict__ W,
                                              const float* __restrict__ att,
                                              const int* __restrict__ row, const int* __restrict__ col,
                                              int* cnt, int* bucket,
                                              uint32* __restrict__ h_pair,
                                              float* __restrict__ s_i, float* __restrict__ s_j,
                                              int N, int E, int ntiles){
  __shared__ __align__(16) unsigned short Blds[128*128];  // W as bf16, [row][swz chunk], 32 KB
  int t = threadIdx.x;
  bool hasTile = ((int)blockIdx.x < ntiles);

  if (hasTile){
    int w = t >> 6, l = t & 63;
    int o = l & 15, lg = l >> 4;
    int n0 = blockIdx.x * 64;

    // stage W into LDS
    #pragma unroll
    for (int i = 0; i < 8; ++i){
      int id = t + i*256;          // 0..2047
      int r  = id >> 4, ck = id & 15;
      int sw = ck ^ (r & 7);
      float4 b0 = *(const float4*)&W[(size_t)r*128 + ck*8];
      float4 b1 = *(const float4*)&W[(size_t)r*128 + ck*8 + 4];
      bf16x8 pb;
      pb[0]=(short)f2bf(b0.x); pb[1]=(short)f2bf(b0.y); pb[2]=(short)f2bf(b0.z); pb[3]=(short)f2bf(b0.w);
      pb[4]=(short)f2bf(b1.x); pb[5]=(short)f2bf(b1.y); pb[6]=(short)f2bf(b1.z); pb[7]=(short)f2bf(b1.w);
      *(bf16x8*)&Blds[r*128 + sw*8] = pb;
    }

    // A-fragments straight from global (rows block-exclusive)
    int arow = n0 + w*16 + o;
    bool rok = (arow < N);
    const float* xr = x + (size_t)arow*128;
    bf16x8 afr[4];
    #pragma unroll
    for (int ks = 0; ks < 4; ++ks){
      float4 a0 = make_float4(0.f,0.f,0.f,0.f), a1 = a0;
      if (rok){
        a0 = *(const float4*)&xr[ks*32 + lg*8];
        a1 = *(const float4*)&xr[ks*32 + lg*8 + 4];
      }
      bf16x8 pa;
      pa[0]=(short)f2bf(a0.x); pa[1]=(short)f2bf(a0.y); pa[2]=(short)f2bf(a0.z); pa[3]=(short)f2bf(a0.w);
      pa[4]=(short)f2bf(a1.x); pa[5]=(short)f2bf(a1.y); pa[6]=(short)f2bf(a1.z); pa[7]=(short)f2bf(a1.w);
      afr[ks] = pa;
    }
    __syncthreads();

    f32x4 acc[8];
    #pragma unroll
    for (int cf = 0; cf < 8; ++cf) acc[cf] = (f32x4){0.f,0.f,0.f,0.f};

    #pragma unroll
    for (int ks = 0; ks < 4; ++ks){
      int ckk = ks*4 + lg;
      #pragma unroll
      for (int cf = 0; cf < 8; ++cf){
        int rb = cf*16 + o;
        bf16x8 bfr = *(const bf16x8*)&Blds[rb*128 + (ckk ^ (rb & 7))*8];
        acc[cf] = __builtin_amdgcn_mfma_f32_16x16x32_bf16(afr[ks], bfr, acc[cf], 0, 0, 0);
      }
    }

    // att weights for this lane's column o
    float ai0[4], ai1[4], aj0[4], aj1[4];
    #pragma unroll
    for (int hd = 0; hd < 4; ++hd){
      ai0[hd] = att[hd*64 + o];
      ai1[hd] = att[hd*64 + 16 + o];
      aj0[hd] = att[hd*64 + 32 + o];
      aj1[hd] = att[hd*64 + 48 + o];
    }

    // epilogue: D row = w*16 + lg*4 + q, col = cf*16 + o
    #pragma unroll
    for (int q = 0; q < 4; ++q){
      int node = n0 + w*16 + lg*4 + q;
      float v[8];
      #pragma unroll
      for (int cf = 0; cf < 8; ++cf) v[cf] = acc[cf][q];
      float pi[4], pj[4];
      #pragma unroll
      for (int hd = 0; hd < 4; ++hd){
        pi[hd] = v[2*hd]*ai0[hd] + v[2*hd+1]*ai1[hd];
        pj[hd] = v[2*hd]*aj0[hd] + v[2*hd+1]*aj1[hd];
      }
      #pragma unroll
      for (int sh = 1; sh < 16; sh <<= 1){
        #pragma unroll
        for (int hd = 0; hd < 4; ++hd){
          pi[hd] += __shfl_xor(pi[hd], sh);
          pj[hd] += __shfl_xor(pj[hd], sh);
        }
      }
      if (node < N){
        #pragma unroll
        for (int hd = 0; hd < 4; ++hd)
          h_pair[(size_t)node*64 + hd*16 + o] = pack_bf2(v[2*hd], v[2*hd+1]);
        if (o == 0){
          *(float4*)&s_i[(size_t)node*4] = make_float4(pi[0], pi[1], pi[2], pi[3]);
          *(float4*)&s_j[(size_t)node*4] = make_float4(pj[0], pj[1], pj[2], pj[3]);
        }
      }
    }
  }

  // fill part (all blocks)
  {
    int k = blockIdx.x & (NPART-1);
    int c = blockIdx.x >> 3;
    int CH = PREP_GRID / NPART;
    int per  = (E + CH - 1) / CH;
    int base = c * per;
    int end  = base + per; if (end > E) end = E;
    int rng  = (N + NPART - 1) / NPART;
    int lo = k * rng, hi = lo + rng;
    for (int i = base + t; i < end; i += 256){
      int d = row[i];
      if (d >= lo && d < hi){
        int pos = atomicAdd(&cnt[d], 1);
        if (pos < SLOT-1) bucket[(size_t)d*SLOT + pos] = col[i];
      }
    }
  }
}

// ---------------- fused softmax + gram + weighted aggregation (independent wave per node) ----------------
// softmax mapping: lane l -> head g=l>>4, slot o=l&15 (wave-private LDS, intra-wave fences only).
// gather mapping:  half=l>>5, lw=l&31: lane loads uint2 = h_pair uints (2lw, 2lw+1) of edge 2i+half
//   -> 4 channels {32g2+o0, 32g2+o0+1, 32g2+16+o0, 32g2+16+o0+1}, g2=lw>>3, o0=(2lw)&15.
// halves merged by shfl_xor(32); out NT-stored, bucket NT-loaded (preserve L2 for h_pair).

__global__ __launch_bounds__(256) void k_agg(const uint32* __restrict__ h_pair, const float* __restrict__ s_i,
                                             const float* __restrict__ s_j, const int* __restrict__ cnt,
                                             const int* __restrict__ bucket,
                                             const float* __restrict__ bias, float* __restrict__ out,
                                             float* __restrict__ gram_part, int N){
  __shared__ __align__(16) float al[4][SLOT*4];   // per-wave alpha[j][head]
  __shared__ int   cs[4][SLOT];                   // per-wave src*32 (uint2 row offset)
  __shared__ float red[4][10];
  const uint2* hp2 = (const uint2*)h_pair;
  int t = threadIdx.x;
  int w = t >> 6, l = t & 63;
  int g = l >> 4, o = l & 15;        // softmax mapping
  int lw = l & 31, half = l >> 5;    // gather mapping
  int g2 = lw >> 3;
  int o0 = (2*lw) & 15;
  int cbase = 32*g2 + (half << 4) + o0;
  float2 bv = *(const float2*)&bias[cbase];
  float ga[10];
  #pragma unroll
  for (int p = 0; p < 10; ++p) ga[p] = 0.f;
  int TW = gridDim.x * 4;

  for (int n = blockIdx.x*4 + w; n < N; n += TW){
    int dc = cnt[n]; if (dc > SLOT-1) dc = SLOT-1;
    int d  = dc + 1;                               // + self loop (implicit, last slot)
    float4 si = *(const float4*)&s_i[(size_t)n*4];
    if (l < d){
      int src = (l < dc) ? __builtin_nontemporal_load(&bucket[(size_t)n*SLOT + l]) : n;
      cs[w][l] = src << 5;                         // uint2 row offset
      float4 sj = *(const float4*)&s_j[(size_t)src*4];
      float4 e;
      e.x = si.x + sj.x; e.y = si.y + sj.y; e.z = si.z + sj.z; e.w = si.w + sj.w;
      e.x = e.x >= 0.f ? e.x : 0.2f*e.x;
      e.y = e.y >= 0.f ? e.y : 0.2f*e.y;
      e.z = e.z >= 0.f ? e.z : 0.2f*e.z;
      e.w = e.w >= 0.f ? e.w : 0.2f*e.w;
      *(float4*)&al[w][l*4] = e;
    }
    if ((d & 1) && l == d){                        // pad edge for odd d: alpha 0, valid addr
      cs[w][l] = n << 5;
      *(float4*)&al[w][l*4] = make_float4(0.f,0.f,0.f,0.f);
    }
    lds_fence();
    // per-head softmax: 16 lanes per head, d <= 64 -> at most 4 strided slots
    float m = -3.4e38f;
    for (int j = o; j < d; j += 16) m = fmaxf(m, al[w][j*4 + g]);
    #pragma unroll
    for (int sh = 1; sh < 16; sh <<= 1) m = fmaxf(m, __shfl_xor(m, sh));
    float sum = 0.f;
    for (int j = o; j < d; j += 16){
      float v = __expf(al[w][j*4 + g] - m);
      al[w][j*4 + g] = v;
      sum += v;
    }
    #pragma unroll
    for (int sh = 1; sh < 16; sh <<= 1) sum += __shfl_xor(sum, sh);
    float r = 1.f/(sum + 1e-16f);
    for (int j = o; j < d; j += 16) al[w][j*4 + g] *= r;
    lds_fence();
    // gram partials (single shot: d <= 64); pad slot has alpha 0 and j<d anyway
    if (l < d){
      float4 a = *(const float4*)&al[w][l*4];
      ga[0] += a.x*a.x; ga[1] += a.x*a.y; ga[2] += a.x*a.z; ga[3] += a.x*a.w;
      ga[4] += a.y*a.y; ga[5] += a.y*a.z; ga[6] += a.y*a.w;
      ga[7] += a.z*a.z; ga[8] += a.z*a.w;
      ga[9] += a.w*a.w;
    }
    // half-wave gather: two edges per iteration across the wave, 4-deep unroll
    float a0 = 0.f, a1 = 0.f, a2 = 0.f, a3 = 0.f;
    const float* alw = &al[w][0];
    const int*   csw = &cs[w][0];
    int npair = (d + 1) >> 1;
    int i = 0;
    for (; i + 4 <= npair; i += 4){
      int e0 = 2*i + half, e1 = e0 + 2, e2 = e0 + 4, e3 = e0 + 6;
      int s0 = csw[e0], s1 = csw[e1], s2 = csw[e2], s3 = csw[e3];
      float w0 = alw[e0*4 + g2], w1 = alw[e1*4 + g2];
      float w2 = alw[e2*4 + g2], w3 = alw[e3*4 + g2];
      uint2 v0 = hp2[(size_t)(uint32)(s0 + lw)];
      uint2 v1 = hp2[(size_t)(uint32)(s1 + lw)];
      uint2 v2 = hp2[(size_t)(uint32)(s2 + lw)];
      uint2 v3 = hp2[(size_t)(uint32)(s3 + lw)];
      a0 += w0 * __uint_as_float(v0.x << 16);  a1 += w0 * __uint_as_float(v0.x & 0xffff0000u);
      a2 += w0 * __uint_as_float(v0.y << 16);  a3 += w0 * __uint_as_float(v0.y & 0xffff0000u);
      a0 += w1 * __uint_as_float(v1.x << 16);  a1 += w1 * __uint_as_float(v1.x & 0xffff0000u);
      a2 += w1 * __uint_as_float(v1.y << 16);  a3 += w1 * __uint_as_float(v1.y & 0xffff0000u);
      a0 += w2 * __uint_as_float(v2.x << 16);  a1 += w2 * __uint_as_float(v2.x & 0xffff0000u);
      a2 += w2 * __uint_as_float(v2.y << 16);  a3 += w2 * __uint_as_float(v2.y & 0xffff0000u);
      a0 += w3 * __uint_as_float(v3.x << 16);  a1 += w3 * __uint_as_float(v3.x & 0xffff0000u);
      a2 += w3 * __uint_as_float(v3.y << 16);  a3 += w3 * __uint_as_float(v3.y & 0xffff0000u);
    }
    for (; i < npair; ++i){
      int e = 2*i + half;
      float aw = alw[e*4 + g2];
      uint2 v = hp2[(size_t)(uint32)(csw[e] + lw)];
      a0 += aw * __uint_as_float(v.x << 16);  a1 += aw * __uint_as_float(v.x & 0xffff0000u);
      a2 += aw * __uint_as_float(v.y << 16);  a3 += aw * __uint_as_float(v.y & 0xffff0000u);
    }
    // merge even/odd-edge partials across halves
    a0 += __shfl_xor(a0, 32);
    a1 += __shfl_xor(a1, 32);
    a2 += __shfl_xor(a2, 32);
    a3 += __shfl_xor(a3, 32);
    // half 0 stores channels (32g2+o0, +1); half 1 stores (32g2+16+o0, +1)
    union { float f[2]; uint64 u; } st;
    st.f[0] = (half ? a1 : a0) + bv.x;
    st.f[1] = (half ? a3 : a2) + bv.y;
    __builtin_nontemporal_store(st.u, (uint64*)&out[(size_t)n*128 + cbase]);
    lds_fence();                                   // WAR guard before next staging write
  }
  __syncthreads();
  #pragma unroll
  for (int p = 0; p < 10; ++p){
    float v = ga[p];
    #pragma unroll
    for (int sh = 1; sh < 64; sh <<= 1) v += __shfl_xor(v, sh);
    ga[p] = v;
  }
  if (l == 0){
    #pragma unroll
    for (int p = 0; p < 10; ++p) red[w][p] = ga[p];
  }
  __syncthreads();
  if (t == 0){
    #pragma unroll
    for (int p = 0; p < 10; ++p)
      gram_part[(size_t)blockIdx.x*10 + p] = red[0][p] + red[1][p] + red[2][p] + red[3][p];
  }
}

// ---------------- gram reduce + diversity loss ----------------

__global__ __launch_bounds__(256) void k_final(const float* __restrict__ gram_part, int nparts,
                                               float* __restrict__ loss){
  __shared__ float red[4][10];
  int t = threadIdx.x;
  float acc[10];
  #pragma unroll
  for (int p = 0; p < 10; ++p) acc[p] = 0.f;
  for (int i = t; i < nparts; i += 256){
    #pragma unroll
    for (int p = 0; p < 10; ++p) acc[p] += gram_part[(size_t)i*10 + p];
  }
  #pragma unroll
  for (int p = 0; p < 10; ++p){
    float v = acc[p];
    #pragma unroll
    for (int sh = 1; sh < 64; sh <<= 1) v += __shfl_xor(v, sh);
    acc[p] = v;
  }
  if ((t & 63) == 0){
    #pragma unroll
    for (int p = 0; p < 10; ++p) red[t >> 6][p] = acc[p];
  }
  __syncthreads();
  if (t == 0){
    float gs[10];
    #pragma unroll
    for (int p = 0; p < 10; ++p) gs[p] = red[0][p] + red[1][p] + red[2][p] + red[3][p];
    float G[4][4];
    G[0][0]=gs[0]; G[0][1]=gs[1]; G[0][2]=gs[2]; G[0][3]=gs[3];
    G[1][0]=gs[1]; G[1][1]=gs[4]; G[1][2]=gs[5]; G[1][3]=gs[6];
    G[2][0]=gs[2]; G[2][1]=gs[5]; G[2][2]=gs[7]; G[2][3]=gs[8];
    G[3][0]=gs[3]; G[3][1]=gs[6]; G[3][2]=gs[8]; G[3][3]=gs[9];
    float nr[4];
    for (int i = 0; i < 4; ++i) nr[i] = sqrtf(G[i][i]);
    float ssum = 0.f;
    for (int i = 0; i < 4; ++i)
      for (int j = 0; j < 4; ++j)
        if (i != j) ssum += G[i][j] / fmaxf(nr[i]*nr[j], 1e-8f);
    loss[0] = ssum * (0.1f/16.f);
  }
}

// ---------------- launch ----------------

extern "C" void kernel_launch(void* const* d_in, const int* in_sizes, int n_in,
                              void* d_out, int out_size, void* d_ws, size_t ws_size,
                              hipStream_t stream){
  const float* x    = (const float*)d_in[0];
  const int*   edge = (const int*)d_in[1];
  const float* W    = (const float*)d_in[2];
  const float* att  = (const float*)d_in[3];
  const float* bias = (const float*)d_in[4];
  int N = in_sizes[0] / 128;
  int E = in_sizes[1] / 2;
  const int* row = edge;       // destinations
  const int* col = edge + E;   // sources
  float* out  = (float*)d_out;
  float* loss = out + (size_t)N*HC;

  char* wsb = (char*)d_ws;
  size_t off = 0;
  auto alloc = [&](size_t bytes)->void*{
    size_t o = (off + 255) & ~(size_t)255;
    off = o + bytes;
    return (void*)(wsb + o);
  };
  uint32* h_pair   = (uint32*)alloc((size_t)N*64*sizeof(uint32));
  float* s_i       = (float*)alloc((size_t)N*4*sizeof(float));
  float* s_j       = (float*)alloc((size_t)N*4*sizeof(float));
  int*   cnt       = (int*)alloc((size_t)N*sizeof(int));
  int*   bucket    = (int*)alloc((size_t)N*SLOT*sizeof(int));
  float* gram_part = (float*)alloc((size_t)AGG_BLOCKS*10*sizeof(float));
  (void)ws_size; (void)n_in; (void)out_size;

  hipMemsetAsync(cnt, 0, (size_t)N*sizeof(int), stream);
  int ntiles = (N+63)/64;
  k_prep<<<PREP_GRID,256,0,stream>>>(x, W, att, row, col, cnt, bucket, h_pair, s_i, s_j, N, E, ntiles);
  k_agg<<<AGG_BLOCKS,256,0,stream>>>(h_pair, s_i, s_j, cnt, bucket, bias, out, gram_part, N);
  k_final<<<1,256,0,stream>>>(gram_part, AGG_BLOCKS, loss);
}